// Round 12
// baseline (248.187 us; speedup 1.0000x reference)
//
#include <hip/hip_runtime.h>

#define NN    4096
#define NE    5
#define NC    2
#define FINF  128
#define FOUTF 64
#define CAP   384

// ---------------- workspace layout (bytes) ----------------
// cnt   @ 0        : 16384
// epack @ 16384    : NN*CAP*16 = 25165824   (int4: u, wA pair, wB pair, wC pair; fp16)
// DdA   @ 25182208 : 32768
// Dd1   @ 25214976 : 32768
// hh    @ 25247744 : NN*FINF*2 = 1048576    (fp16 h panel)
// XhA   @ 26296320 : NC*NN*FINF*2 = 2097152
// Xh1   @ 28393472 : 2097152
// end ~ 30.5 MB

union f16u { unsigned short s; _Float16 h; };

static __device__ __forceinline__ unsigned short f2h(float x)
{
    f16u u; u.h = (_Float16)x; return u.s;
}
static __device__ __forceinline__ float lo16f(unsigned x)
{
    f16u u; u.s = (unsigned short)(x & 0xffff); return (float)u.h;
}
static __device__ __forceinline__ float hi16f(unsigned x)
{
    f16u u; u.s = (unsigned short)(x >> 16); return (float)u.h;
}
static __device__ __forceinline__ unsigned pack2h(float a, float b)
{
    return (unsigned)f2h(a) | ((unsigned)f2h(b) << 16);
}

// blocks 0..3: zero cnt; blocks 4..515: f32 h -> fp16 hh
__global__ __launch_bounds__(256) void init_misc(int4* __restrict__ cnt4,
                                                 const float4* __restrict__ h4,
                                                 uint2* __restrict__ hh)
{
    int b = blockIdx.x;
    if (b < 4) {
        cnt4[b * 256 + threadIdx.x] = int4{0, 0, 0, 0};
    } else {
        int i = (b - 4) * 256 + threadIdx.x;        // 131072 float4s
        float4 f = h4[i];
        uint2 r;
        r.x = pack2h(f.x, f.y);
        r.y = pack2h(f.z, f.w);
        hh[i] = r;
    }
}

// Coalesced float4 streaming reads of A (5 slices), global-atomic append,
// ONE 16-byte packed store per edge.
__global__ __launch_bounds__(256) void build_csc(
    const float* __restrict__ A,
    const float* __restrict__ W1_0,
    const float* __restrict__ W2_0,
    const float* __restrict__ W1_1,
    int*  __restrict__ cnt,
    int4* __restrict__ epack)
{
    float fA0[NE], fA1[NE], fB0[NE], fB1[NE], fC0[NE], fC1[NE];
#pragma unroll
    for (int e = 0; e < NE; ++e) {
        fA0[e] = W1_0[e];      fA1[e] = W1_0[NE + e];
        fB0[e] = W2_0[e];      fB1[e] = W2_0[NE + e];
        fC0[e] = W1_1[e];      fC1[e] = W1_1[NE + e];
    }

    const size_t S = (size_t)NN * NN / 4;   // float4 per e-slice
    const float4* A4 = (const float4*)A;
    size_t stride = (size_t)gridDim.x * blockDim.x;
    for (size_t i = (size_t)blockIdx.x * blockDim.x + threadIdx.x; i < S; i += stride) {
        float4 q0 = A4[i];
        float4 q1 = A4[i + S];
        float4 q2 = A4[i + 2 * S];
        float4 q3 = A4[i + 3 * S];
        float4 q4 = A4[i + 4 * S];
        int u  = (int)(i >> 10);            // 1024 float4 per row
        int v0 = ((int)i & 1023) << 2;
#define DO_COMP(comp, joff)                                                      \
        {                                                                        \
            float a0 = q0.comp, a1 = q1.comp, a2 = q2.comp,                      \
                  a3 = q3.comp, a4 = q4.comp;                                    \
            if (a0 != 0.f || a1 != 0.f || a2 != 0.f || a3 != 0.f || a4 != 0.f) { \
                float sA0 = fA0[0]*a0 + fA0[1]*a1 + fA0[2]*a2 + fA0[3]*a3 + fA0[4]*a4; \
                float sA1 = fA1[0]*a0 + fA1[1]*a1 + fA1[2]*a2 + fA1[3]*a3 + fA1[4]*a4; \
                float sB0 = fB0[0]*a0 + fB0[1]*a1 + fB0[2]*a2 + fB0[3]*a3 + fB0[4]*a4; \
                float sB1 = fB1[0]*a0 + fB1[1]*a1 + fB1[2]*a2 + fB1[3]*a3 + fB1[4]*a4; \
                float sC0 = fC0[0]*a0 + fC0[1]*a1 + fC0[2]*a2 + fC0[3]*a3 + fC0[4]*a4; \
                float sC1 = fC1[0]*a0 + fC1[1]*a1 + fC1[2]*a2 + fC1[3]*a3 + fC1[4]*a4; \
                int v = v0 + joff;                                               \
                int pos = atomicAdd(&cnt[v], 1);                                 \
                if (pos < CAP) {                                                 \
                    int4 rec;                                                    \
                    rec.x = u;                                                   \
                    rec.y = (int)pack2h(__expf(sA0), __expf(sA1));               \
                    rec.z = (int)pack2h(__expf(sB0), __expf(sB1));               \
                    rec.w = (int)pack2h(sC0, sC1);                               \
                    epack[v * CAP + pos] = rec;                                  \
                }                                                                \
            }                                                                    \
        }
        DO_COMP(x, 0)
        DO_COMP(y, 1)
        DO_COMP(z, 2)
        DO_COMP(w, 3)
#undef DO_COMP
    }
}

// One workgroup (256 threads) per column v; both channels; GCN epilogue fused.
// (R6 structure — best measured: 212 us total.)
template<int STAGE>
__global__ __launch_bounds__(256) void spmm_col(
    const int*   __restrict__ cnt,
    const int4*  __restrict__ epack,
    const unsigned short* __restrict__ Xh_in, // stage0: [NN][128]; else [NC][NN][128]
    const float* __restrict__ Dd_in,    // stages 1/2: [NC][NN]
    const float* __restrict__ gW,       // [NC][FINF][FOUTF]
    const float* __restrict__ gb,       // [NC][FOUTF]
    float*       __restrict__ out,      // [NC][3][NN][FOUTF]
    unsigned short* __restrict__ Xh_out,// stages 0/1
    float*       __restrict__ Dd_out)   // stages 0/1
{
    int v = blockIdx.x;
    int n = cnt[v];
    if (n > CAP) n = CAP;

    __shared__ float4 s_e[CAP];          // {u bits, w0, w1, pad}
    __shared__ float  s_red[4];          // sum0, sum1, d0, d1
    __shared__ float4 s_acc[NC][8][32];  // 8 KB partials
    __shared__ float  s_y[NC][FINF];
    __shared__ float  s_inv[NC];

    int tid = threadIdx.x;
    if (tid < 4) s_red[tid] = 0.f;
    __syncthreads();

    float l0 = 0.f, l1 = 0.f, ld0 = 0.f, ld1 = 0.f;
    for (int i = tid; i < n; i += 256) {
        int4 E = epack[v * CAP + i];
        unsigned wb = (unsigned)((STAGE == 0) ? E.y : (STAGE == 1) ? E.z : E.w);
        float w0 = lo16f(wb), w1 = hi16f(wb);
        s_e[i] = float4{__int_as_float(E.x), w0, w1, 0.f};
        l0 += w0;
        l1 += w1;
        if (STAGE != 0) {
            ld0 += w0 * Dd_in[E.x];
            ld1 += w1 * Dd_in[NN + E.x];
        }
    }
    if (STAGE == 0) { ld0 = l0; ld1 = l1; }

#pragma unroll
    for (int m = 32; m >= 1; m >>= 1) {
        l0  += __shfl_xor(l0,  m);
        l1  += __shfl_xor(l1,  m);
        ld0 += __shfl_xor(ld0, m);
        ld1 += __shfl_xor(ld1, m);
    }
    if ((tid & 63) == 0) {
        atomicAdd(&s_red[0], l0);
        atomicAdd(&s_red[1], l1);
        atomicAdd(&s_red[2], ld0);
        atomicAdd(&s_red[3], ld1);
    }
    __syncthreads();

    int grp = tid >> 5, lane = tid & 31;
    float4 a0 = {0.f, 0.f, 0.f, 0.f};
    float4 a1 = {0.f, 0.f, 0.f, 0.f};

    if (STAGE == 0) {
        const uint2* H = (const uint2*)Xh_in;              // [NN][32]
#pragma unroll 2
        for (int i = grp; i < n; i += 8) {
            float4 e = s_e[i];
            uint2 b = H[(size_t)__float_as_int(e.x) * 32 + lane];
            float x0 = lo16f(b.x), x1 = hi16f(b.x);
            float x2 = lo16f(b.y), x3 = hi16f(b.y);
            a0.x += e.y * x0; a0.y += e.y * x1; a0.z += e.y * x2; a0.w += e.y * x3;
            a1.x += e.z * x0; a1.y += e.z * x1; a1.z += e.z * x2; a1.w += e.z * x3;
        }
    } else {
        const uint2* P0 = (const uint2*)Xh_in;             // [NN][32] per channel
        const uint2* P1 = P0 + (size_t)NN * 32;
#pragma unroll 2
        for (int i = grp; i < n; i += 8) {
            float4 e = s_e[i];
            int u = __float_as_int(e.x);
            uint2 b0 = P0[(size_t)u * 32 + lane];
            uint2 b1 = P1[(size_t)u * 32 + lane];
            a0.x += e.y * lo16f(b0.x); a0.y += e.y * hi16f(b0.x);
            a0.z += e.y * lo16f(b0.y); a0.w += e.y * hi16f(b0.y);
            a1.x += e.z * lo16f(b1.x); a1.y += e.z * hi16f(b1.x);
            a1.z += e.z * lo16f(b1.y); a1.w += e.z * hi16f(b1.y);
        }
    }

    s_acc[0][grp][lane] = a0;
    s_acc[1][grp][lane] = a1;
    __syncthreads();

    int c = tid >> 7, f = tid & 127;
    {
        const float* base = (const float*)s_acc[c];      // [8][128]
        float s = 0.f;
#pragma unroll
        for (int g = 0; g < 8; ++g) s += base[g * 128 + f];

        float inv = 1.f;
        if (STAGE < 2 && n > 0) inv = 1.f / s_red[c];
        float val = s * inv;

        s_y[c][f] = val;
        if (STAGE < 2)
            Xh_out[((size_t)c * NN + v) * FINF + f] = f2h(val);
        if (f == 0) {
            float dvn = s_red[2 + c] * inv;
            s_inv[c] = (dvn != 0.f) ? (1.f / dvn) : 1.f;
            if (STAGE < 2) Dd_out[c * NN + v] = dvn;
        }
    }
    __syncthreads();

    // Phase 4: fused GraphConv epilogue (128 threads: (c2, o))
    if (tid < 2 * FOUTF) {
        int c2 = tid >> 6, o = tid & 63;
        const float* w = gW + (size_t)c2 * FINF * FOUTF + o;
        const float* y = s_y[c2];
        float acc = 0.f;
#pragma unroll 8
        for (int f2 = 0; f2 < FINF; ++f2)
            acc += y[f2] * w[(size_t)f2 * FOUTF];
        float r = acc * s_inv[c2] + gb[c2 * FOUTF + o];
        out[(((size_t)c2 * 3 + STAGE) * NN + v) * FOUTF + o] = fmaxf(r, 0.f);
    }
}

extern "C" void kernel_launch(void* const* d_in, const int* in_sizes, int n_in,
                              void* d_out, int out_size, void* d_ws, size_t ws_size,
                              hipStream_t stream)
{
    const float* A     = (const float*)d_in[0];
    const float* h     = (const float*)d_in[1];
    const float* W1_0  = (const float*)d_in[2];
    const float* W2_0  = (const float*)d_in[3];
    const float* W1_1  = (const float*)d_in[4];
    const float* gW    = (const float*)d_in[5];
    const float* gb    = (const float*)d_in[6];
    float* out = (float*)d_out;

    char* ws = (char*)d_ws;
    int*            cnt   = (int*)(ws);
    int4*           epack = (int4*)(ws + 16384);
    float*          DdA   = (float*)(ws + 25182208);
    float*          Dd1   = (float*)(ws + 25214976);
    uint2*          hh    = (uint2*)(ws + 25247744);
    unsigned short* XhA   = (unsigned short*)(ws + 26296320);
    unsigned short* Xh1   = (unsigned short*)(ws + 28393472);

    init_misc<<<516, 256, 0, stream>>>((int4*)cnt, (const float4*)h, hh);
    build_csc<<<2048, 256, 0, stream>>>(A, W1_0, W2_0, W1_1, cnt, epack);

    // Stage A: softmax wA, gather fp16 hh -> out[:,0], XhA, DdA
    spmm_col<0><<<NN, 256, 0, stream>>>(cnt, epack, (const unsigned short*)hh, nullptr, gW, gb, out, XhA, DdA);
    // Stage B: softmax wB, gather XhA     -> out[:,1], Xh1, Dd1
    spmm_col<1><<<NN, 256, 0, stream>>>(cnt, epack, XhA, DdA, gW, gb, out, Xh1, Dd1);
    // Stage C: raw wC, gather Xh1         -> out[:,2]
    spmm_col<2><<<NN, 256, 0, stream>>>(cnt, epack, Xh1, Dd1, gW, gb, out, nullptr, nullptr);
    // TIMING PROBE (this round only): stage C is idempotent (reads cnt/epack/
    // Xh1/Dd1, rewrites identical out[:,2]). Duplicate launch => dur delta vs
    // the 212us R6 baseline measures ONE spmm stage's true cost.
    spmm_col<2><<<NN, 256, 0, stream>>>(cnt, epack, Xh1, Dd1, gW, gb, out, nullptr, nullptr);
}

// Round 13
// 213.230 us; speedup vs baseline: 1.1639x; 1.1639x over previous
//
#include <hip/hip_runtime.h>

#define NN    4096
#define NE    5
#define NC    2
#define FINF  128
#define FOUTF 64
#define CAP   384

// ---------------- workspace layout (bytes) ----------------
// cnt   @ 0        : 16384
// epack @ 16384    : NN*CAP*16 = 25165824   (int4: u, wA pair, wB pair, wC pair; fp16)
// DdA   @ 25182208 : 32768
// Dd1   @ 25214976 : 32768
// hh    @ 25247744 : NN*FINF*2 = 1048576    (fp16 h panel)
// XhA   @ 26296320 : NC*NN*FINF*2 = 2097152
// Xh1   @ 28393472 : 2097152
// end ~ 30.5 MB

union f16u { unsigned short s; _Float16 h; };

static __device__ __forceinline__ unsigned short f2h(float x)
{
    f16u u; u.h = (_Float16)x; return u.s;
}
static __device__ __forceinline__ float lo16f(unsigned x)
{
    f16u u; u.s = (unsigned short)(x & 0xffff); return (float)u.h;
}
static __device__ __forceinline__ float hi16f(unsigned x)
{
    f16u u; u.s = (unsigned short)(x >> 16); return (float)u.h;
}
static __device__ __forceinline__ unsigned pack2h(float a, float b)
{
    return (unsigned)f2h(a) | ((unsigned)f2h(b) << 16);
}

// blocks 0..3: zero cnt; blocks 4..515: f32 h -> fp16 hh
__global__ __launch_bounds__(256) void init_misc(int4* __restrict__ cnt4,
                                                 const float4* __restrict__ h4,
                                                 uint2* __restrict__ hh)
{
    int b = blockIdx.x;
    if (b < 4) {
        cnt4[b * 256 + threadIdx.x] = int4{0, 0, 0, 0};
    } else {
        int i = (b - 4) * 256 + threadIdx.x;        // 131072 float4s
        float4 f = h4[i];
        uint2 r;
        r.x = pack2h(f.x, f.y);
        r.y = pack2h(f.z, f.w);
        hh[i] = r;
    }
}

// Coalesced float4 streaming reads of A (5 slices), global-atomic append,
// ONE 16-byte packed store per edge.
__global__ __launch_bounds__(256) void build_csc(
    const float* __restrict__ A,
    const float* __restrict__ W1_0,
    const float* __restrict__ W2_0,
    const float* __restrict__ W1_1,
    int*  __restrict__ cnt,
    int4* __restrict__ epack)
{
    float fA0[NE], fA1[NE], fB0[NE], fB1[NE], fC0[NE], fC1[NE];
#pragma unroll
    for (int e = 0; e < NE; ++e) {
        fA0[e] = W1_0[e];      fA1[e] = W1_0[NE + e];
        fB0[e] = W2_0[e];      fB1[e] = W2_0[NE + e];
        fC0[e] = W1_1[e];      fC1[e] = W1_1[NE + e];
    }

    const size_t S = (size_t)NN * NN / 4;   // float4 per e-slice
    const float4* A4 = (const float4*)A;
    size_t stride = (size_t)gridDim.x * blockDim.x;
    for (size_t i = (size_t)blockIdx.x * blockDim.x + threadIdx.x; i < S; i += stride) {
        float4 q0 = A4[i];
        float4 q1 = A4[i + S];
        float4 q2 = A4[i + 2 * S];
        float4 q3 = A4[i + 3 * S];
        float4 q4 = A4[i + 4 * S];
        int u  = (int)(i >> 10);            // 1024 float4 per row
        int v0 = ((int)i & 1023) << 2;
#define DO_COMP(comp, joff)                                                      \
        {                                                                        \
            float a0 = q0.comp, a1 = q1.comp, a2 = q2.comp,                      \
                  a3 = q3.comp, a4 = q4.comp;                                    \
            if (a0 != 0.f || a1 != 0.f || a2 != 0.f || a3 != 0.f || a4 != 0.f) { \
                float sA0 = fA0[0]*a0 + fA0[1]*a1 + fA0[2]*a2 + fA0[3]*a3 + fA0[4]*a4; \
                float sA1 = fA1[0]*a0 + fA1[1]*a1 + fA1[2]*a2 + fA1[3]*a3 + fA1[4]*a4; \
                float sB0 = fB0[0]*a0 + fB0[1]*a1 + fB0[2]*a2 + fB0[3]*a3 + fB0[4]*a4; \
                float sB1 = fB1[0]*a0 + fB1[1]*a1 + fB1[2]*a2 + fB1[3]*a3 + fB1[4]*a4; \
                float sC0 = fC0[0]*a0 + fC0[1]*a1 + fC0[2]*a2 + fC0[3]*a3 + fC0[4]*a4; \
                float sC1 = fC1[0]*a0 + fC1[1]*a1 + fC1[2]*a2 + fC1[3]*a3 + fC1[4]*a4; \
                int v = v0 + joff;                                               \
                int pos = atomicAdd(&cnt[v], 1);                                 \
                if (pos < CAP) {                                                 \
                    int4 rec;                                                    \
                    rec.x = u;                                                   \
                    rec.y = (int)pack2h(__expf(sA0), __expf(sA1));               \
                    rec.z = (int)pack2h(__expf(sB0), __expf(sB1));               \
                    rec.w = (int)pack2h(sC0, sC1);                               \
                    epack[v * CAP + pos] = rec;                                  \
                }                                                                \
            }                                                                    \
        }
        DO_COMP(x, 0)
        DO_COMP(y, 1)
        DO_COMP(z, 2)
        DO_COMP(w, 3)
#undef DO_COMP
    }
}

// One workgroup (256 threads) per column v; both channels; GCN epilogue fused.
// Phase 2 is dual-edge unrolled (edges i and i+8 per iteration, stride 16):
// 4 independent row loads in flight per thread to cover LLC latency.
template<int STAGE>
__global__ __launch_bounds__(256) void spmm_col(
    const int*   __restrict__ cnt,
    const int4*  __restrict__ epack,
    const unsigned short* __restrict__ Xh_in, // stage0: [NN][128]; else [NC][NN][128]
    const float* __restrict__ Dd_in,    // stages 1/2: [NC][NN]
    const float* __restrict__ gW,       // [NC][FINF][FOUTF]
    const float* __restrict__ gb,       // [NC][FOUTF]
    float*       __restrict__ out,      // [NC][3][NN][FOUTF]
    unsigned short* __restrict__ Xh_out,// stages 0/1
    float*       __restrict__ Dd_out)   // stages 0/1
{
    int v = blockIdx.x;
    int n = cnt[v];
    if (n > CAP) n = CAP;

    __shared__ float4 s_e[CAP];          // {u bits, w0, w1, pad}
    __shared__ float  s_red[4];          // sum0, sum1, d0, d1
    __shared__ float4 s_acc[NC][8][32];  // 8 KB partials
    __shared__ float  s_y[NC][FINF];
    __shared__ float  s_inv[NC];

    int tid = threadIdx.x;
    if (tid < 4) s_red[tid] = 0.f;
    __syncthreads();

    float l0 = 0.f, l1 = 0.f, ld0 = 0.f, ld1 = 0.f;
    for (int i = tid; i < n; i += 256) {
        int4 E = epack[v * CAP + i];
        unsigned wb = (unsigned)((STAGE == 0) ? E.y : (STAGE == 1) ? E.z : E.w);
        float w0 = lo16f(wb), w1 = hi16f(wb);
        s_e[i] = float4{__int_as_float(E.x), w0, w1, 0.f};
        l0 += w0;
        l1 += w1;
        if (STAGE != 0) {
            ld0 += w0 * Dd_in[E.x];
            ld1 += w1 * Dd_in[NN + E.x];
        }
    }
    if (STAGE == 0) { ld0 = l0; ld1 = l1; }

#pragma unroll
    for (int m = 32; m >= 1; m >>= 1) {
        l0  += __shfl_xor(l0,  m);
        l1  += __shfl_xor(l1,  m);
        ld0 += __shfl_xor(ld0, m);
        ld1 += __shfl_xor(ld1, m);
    }
    if ((tid & 63) == 0) {
        atomicAdd(&s_red[0], l0);
        atomicAdd(&s_red[1], l1);
        atomicAdd(&s_red[2], ld0);
        atomicAdd(&s_red[3], ld1);
    }
    __syncthreads();

    int grp = tid >> 5, lane = tid & 31;
    float4 a0 = {0.f, 0.f, 0.f, 0.f};   // ch0, edge-stream 0
    float4 a1 = {0.f, 0.f, 0.f, 0.f};   // ch1, edge-stream 0
    float4 c0 = {0.f, 0.f, 0.f, 0.f};   // ch0, edge-stream 1
    float4 c1 = {0.f, 0.f, 0.f, 0.f};   // ch1, edge-stream 1

    if (STAGE == 0) {
        const uint2* H = (const uint2*)Xh_in;              // [NN][32]
        int i = grp;
        for (; i + 8 < n; i += 16) {
            float4 e0 = s_e[i];
            float4 e1 = s_e[i + 8];
            uint2 p = H[(size_t)__float_as_int(e0.x) * 32 + lane];
            uint2 q = H[(size_t)__float_as_int(e1.x) * 32 + lane];
            float x0 = lo16f(p.x), x1 = hi16f(p.x), x2 = lo16f(p.y), x3 = hi16f(p.y);
            float y0 = lo16f(q.x), y1 = hi16f(q.x), y2 = lo16f(q.y), y3 = hi16f(q.y);
            a0.x += e0.y * x0; a0.y += e0.y * x1; a0.z += e0.y * x2; a0.w += e0.y * x3;
            a1.x += e0.z * x0; a1.y += e0.z * x1; a1.z += e0.z * x2; a1.w += e0.z * x3;
            c0.x += e1.y * y0; c0.y += e1.y * y1; c0.z += e1.y * y2; c0.w += e1.y * y3;
            c1.x += e1.z * y0; c1.y += e1.z * y1; c1.z += e1.z * y2; c1.w += e1.z * y3;
        }
        for (; i < n; i += 8) {
            float4 e0 = s_e[i];
            uint2 p = H[(size_t)__float_as_int(e0.x) * 32 + lane];
            float x0 = lo16f(p.x), x1 = hi16f(p.x), x2 = lo16f(p.y), x3 = hi16f(p.y);
            a0.x += e0.y * x0; a0.y += e0.y * x1; a0.z += e0.y * x2; a0.w += e0.y * x3;
            a1.x += e0.z * x0; a1.y += e0.z * x1; a1.z += e0.z * x2; a1.w += e0.z * x3;
        }
    } else {
        const uint2* P0 = (const uint2*)Xh_in;             // [NN][32] per channel
        const uint2* P1 = P0 + (size_t)NN * 32;
        int i = grp;
        for (; i + 8 < n; i += 16) {
            float4 e0 = s_e[i];
            float4 e1 = s_e[i + 8];
            size_t r0 = (size_t)__float_as_int(e0.x) * 32 + lane;
            size_t r1 = (size_t)__float_as_int(e1.x) * 32 + lane;
            uint2 p0 = P0[r0];
            uint2 p1 = P1[r0];
            uint2 q0 = P0[r1];
            uint2 q1 = P1[r1];
            a0.x += e0.y * lo16f(p0.x); a0.y += e0.y * hi16f(p0.x);
            a0.z += e0.y * lo16f(p0.y); a0.w += e0.y * hi16f(p0.y);
            a1.x += e0.z * lo16f(p1.x); a1.y += e0.z * hi16f(p1.x);
            a1.z += e0.z * lo16f(p1.y); a1.w += e0.z * hi16f(p1.y);
            c0.x += e1.y * lo16f(q0.x); c0.y += e1.y * hi16f(q0.x);
            c0.z += e1.y * lo16f(q0.y); c0.w += e1.y * hi16f(q0.y);
            c1.x += e1.z * lo16f(q1.x); c1.y += e1.z * hi16f(q1.x);
            c1.z += e1.z * lo16f(q1.y); c1.w += e1.z * hi16f(q1.y);
        }
        for (; i < n; i += 8) {
            float4 e0 = s_e[i];
            size_t r0 = (size_t)__float_as_int(e0.x) * 32 + lane;
            uint2 p0 = P0[r0];
            uint2 p1 = P1[r0];
            a0.x += e0.y * lo16f(p0.x); a0.y += e0.y * hi16f(p0.x);
            a0.z += e0.y * lo16f(p0.y); a0.w += e0.y * hi16f(p0.y);
            a1.x += e0.z * lo16f(p1.x); a1.y += e0.z * hi16f(p1.x);
            a1.z += e0.z * lo16f(p1.y); a1.w += e0.z * hi16f(p1.y);
        }
    }

    a0.x += c0.x; a0.y += c0.y; a0.z += c0.z; a0.w += c0.w;
    a1.x += c1.x; a1.y += c1.y; a1.z += c1.z; a1.w += c1.w;

    s_acc[0][grp][lane] = a0;
    s_acc[1][grp][lane] = a1;
    __syncthreads();

    int c = tid >> 7, f = tid & 127;
    {
        const float* base = (const float*)s_acc[c];      // [8][128]
        float s = 0.f;
#pragma unroll
        for (int g = 0; g < 8; ++g) s += base[g * 128 + f];

        float inv = 1.f;
        if (STAGE < 2 && n > 0) inv = 1.f / s_red[c];
        float val = s * inv;

        s_y[c][f] = val;
        if (STAGE < 2)
            Xh_out[((size_t)c * NN + v) * FINF + f] = f2h(val);
        if (f == 0) {
            float dvn = s_red[2 + c] * inv;
            s_inv[c] = (dvn != 0.f) ? (1.f / dvn) : 1.f;
            if (STAGE < 2) Dd_out[c * NN + v] = dvn;
        }
    }
    __syncthreads();

    // Phase 4: fused GraphConv epilogue (128 threads: (c2, o))
    if (tid < 2 * FOUTF) {
        int c2 = tid >> 6, o = tid & 63;
        const float* w = gW + (size_t)c2 * FINF * FOUTF + o;
        const float* y = s_y[c2];
        float acc = 0.f;
#pragma unroll 8
        for (int f2 = 0; f2 < FINF; ++f2)
            acc += y[f2] * w[(size_t)f2 * FOUTF];
        float r = acc * s_inv[c2] + gb[c2 * FOUTF + o];
        out[(((size_t)c2 * 3 + STAGE) * NN + v) * FOUTF + o] = fmaxf(r, 0.f);
    }
}

extern "C" void kernel_launch(void* const* d_in, const int* in_sizes, int n_in,
                              void* d_out, int out_size, void* d_ws, size_t ws_size,
                              hipStream_t stream)
{
    const float* A     = (const float*)d_in[0];
    const float* h     = (const float*)d_in[1];
    const float* W1_0  = (const float*)d_in[2];
    const float* W2_0  = (const float*)d_in[3];
    const float* W1_1  = (const float*)d_in[4];
    const float* gW    = (const float*)d_in[5];
    const float* gb    = (const float*)d_in[6];
    float* out = (float*)d_out;

    char* ws = (char*)d_ws;
    int*            cnt   = (int*)(ws);
    int4*           epack = (int4*)(ws + 16384);
    float*          DdA   = (float*)(ws + 25182208);
    float*          Dd1   = (float*)(ws + 25214976);
    uint2*          hh    = (uint2*)(ws + 25247744);
    unsigned short* XhA   = (unsigned short*)(ws + 26296320);
    unsigned short* Xh1   = (unsigned short*)(ws + 28393472);

    init_misc<<<516, 256, 0, stream>>>((int4*)cnt, (const float4*)h, hh);
    build_csc<<<2048, 256, 0, stream>>>(A, W1_0, W2_0, W1_1, cnt, epack);

    // Stage A: softmax wA, gather fp16 hh -> out[:,0], XhA, DdA
    spmm_col<0><<<NN, 256, 0, stream>>>(cnt, epack, (const unsigned short*)hh, nullptr, gW, gb, out, XhA, DdA);
    // Stage B: softmax wB, gather XhA     -> out[:,1], Xh1, Dd1
    spmm_col<1><<<NN, 256, 0, stream>>>(cnt, epack, XhA, DdA, gW, gb, out, Xh1, Dd1);
    // Stage C: raw wC, gather Xh1         -> out[:,2]
    spmm_col<2><<<NN, 256, 0, stream>>>(cnt, epack, Xh1, Dd1, gW, gb, out, nullptr, nullptr);
}